// Round 9
// baseline (135.783 us; speedup 1.0000x reference)
//
#include <hip/hip_runtime.h>
#include <hip/hip_bf16.h>

#define B_   128
#define N_   65536
#define F_   512
#define CS   64                  // samples per chunk (per thread)
#define CPR  (N_ / CS)           // 1024 chunks per row == threads per block
#define TPB  1024                // one block = one row
#define NWAVE (TPB / 64)         // 16 waves per block
#define KPOS ((float)(511.0 / 65535.0))
#define INVK ((float)(65535.0 / 511.0))

__device__ __forceinline__ float tanh_map1(float l) { return 2.0f * tanhf(l); }

// Chunk geometry: I (i0 at chunk start), kc (first sample whose i0 is I+1; CS if
// no crossing), exactly matching reference floorf((n0+k)*K). (validated R5/R8)
__device__ __forceinline__ void chunk_geom(int n0, float& pos0, int& I, int& kc) {
    pos0 = (float)n0 * KPOS;
    I = min((int)pos0, F_ - 2);
    int k = (int)ceilf(((float)(I + 1) - pos0) * INVK);
    k = max(0, min(k, CS));
    if (k > 0 && (int)((float)(n0 + k - 1) * KPOS) > I) --k;
    else if (k < CS && (int)((float)(n0 + k) * KPOS) <= I) ++k;
    if ((int)pos0 > F_ - 2) k = CS;
    if (I == F_ - 2) {
        if ((float)n0 * KPOS >= (float)(F_ - 1)) k = CS;
    }
    kc = k;
}

// One block per batch row. Full row scan is intra-block:
//   per-thread compose (CS=64) -> wave shuffle-scan (6 rounds, no barriers)
//   -> 16 wave aggregates in LDS -> per-wave v-fold -> recurrence + FIR.
// No global intermediates; x read from global twice (2nd hits L2).
__global__ __launch_bounds__(TPB, 4) void fused_row(const float* __restrict__ x,
                                                    const float* __restrict__ logits,
                                                    float* __restrict__ out) {
    __shared__ float wagg[NWAVE][6];
    __shared__ float wpv[NWAVE][2];
    int tid  = threadIdx.x;
    int b    = blockIdx.x;
    int lane = tid & 63;
    int wid  = tid >> 6;
    int n0   = tid * CS;

    float pos0; int I, kc;
    chunk_geom(n0, pos0, I, kc);
    int I2 = min(I + 2, F_ - 1);
    const float* Lg = logits + (size_t)b * F_ * 5;

    // a-coefficient triangle map (computed ONCE per thread)
    float a1A = tanh_map1(Lg[I * 5 + 0]);
    float a1B = tanh_map1(Lg[(I + 1) * 5 + 0]);
    float a1C = tanh_map1(Lg[I2 * 5 + 0]);
    float t1A = tanhf(Lg[I * 5 + 1]);
    float t1B = tanhf(Lg[(I + 1) * 5 + 1]);
    float t1C = tanhf(Lg[I2 * 5 + 1]);
    float a2A = 0.5f * ((2.0f - fabsf(a1A)) * t1A + fabsf(a1A));
    float a2B = 0.5f * ((2.0f - fabsf(a1B)) * t1B + fabsf(a1B));
    float a2C = 0.5f * ((2.0f - fabsf(a1C)) * t1C + fabsf(a1C));

    float If = (float)I;
    float C1  = fmaf(pos0 - If,        a1B - a1A, a1A), D1  = KPOS * (a1B - a1A);
    float C1b = fmaf(pos0 - If - 1.f,  a1C - a1B, a1B), D1b = KPOS * (a1C - a1B);
    float C2  = fmaf(pos0 - If,        a2B - a2A, a2A), D2  = KPOS * (a2B - a2A);
    float C2b = fmaf(pos0 - If - 1.f,  a2C - a2B, a2B), D2b = KPOS * (a2C - a2B);

    // ---- compose this chunk's affine transform (direct 16x float4 reads) ----
    const float4* xp = (const float4*)x + ((size_t)b * N_ + n0) / 4;
    float A00 = 1.f, A01 = 0.f, A10 = 0.f, A11 = 1.f, v0 = 0.f, v1 = 0.f;
    #pragma unroll
    for (int j = 0; j < CS / 4; ++j) {
        float4 xv = xp[j];
        #pragma unroll
        for (int u = 0; u < 4; ++u) {
            int k = j * 4 + u;
            float xn = (&xv.x)[u];
            bool sB = (k >= kc);
            float kf = (float)k;
            float a1 = fmaf(kf, sB ? D1b : D1, sB ? C1b : C1);
            float a2 = fmaf(kf, sB ? D2b : D2, sB ? C2b : C2);
            float nA00 = fmaf(-a2, A10, -a1 * A00);
            float nA01 = fmaf(-a2, A11, -a1 * A01);
            float nv0  = fmaf(-a2, v1, fmaf(-a1, v0, xn));
            A10 = A00; A11 = A01; v1 = v0;
            A00 = nA00; A01 = nA01; v0 = nv0;
        }
    }

    // ---- wave-level inclusive scan (6 shuffle rounds, no barriers) ----
    #pragma unroll
    for (int d = 1; d < 64; d <<= 1) {
        float f00 = __shfl_up(A00, d);
        float f01 = __shfl_up(A01, d);
        float f10 = __shfl_up(A10, d);
        float f11 = __shfl_up(A11, d);
        float fv0 = __shfl_up(v0, d);
        float fv1 = __shfl_up(v1, d);
        if (lane >= d) {
            float n00 = A00 * f00 + A01 * f10;
            float n01 = A00 * f01 + A01 * f11;
            float n10 = A10 * f00 + A11 * f10;
            float n11 = A10 * f01 + A11 * f11;
            float nv0 = A00 * fv0 + A01 * fv1 + v0;
            float nv1 = A10 * fv0 + A11 * fv1 + v1;
            A00 = n00; A01 = n01; A10 = n10; A11 = n11; v0 = nv0; v1 = nv1;
        }
    }

    // lane-exclusive prefix (inclusive of lane-1; identity at lane 0)
    float e00 = __shfl_up(A00, 1), e01 = __shfl_up(A01, 1);
    float e10 = __shfl_up(A10, 1), e11 = __shfl_up(A11, 1);
    float ev0 = __shfl_up(v0, 1),  ev1 = __shfl_up(v1, 1);
    if (lane == 0) { e00 = 1.f; e01 = 0.f; e10 = 0.f; e11 = 1.f; ev0 = 0.f; ev1 = 0.f; }

    // wave aggregate -> LDS
    if (lane == 63) {
        wagg[wid][0] = A00; wagg[wid][1] = A01; wagg[wid][2] = A10;
        wagg[wid][3] = A11; wagg[wid][4] = v0;  wagg[wid][5] = v1;
    }
    __syncthreads();

    // per-wave exclusive prefix applied to row-start state (0,0): only v needed
    if (lane == 0) {
        float s0 = 0.f, s1 = 0.f;
        for (int p = 0; p < wid; ++p) {
            float n0s = wagg[p][0] * s0 + wagg[p][1] * s1 + wagg[p][4];
            float n1s = wagg[p][2] * s0 + wagg[p][3] * s1 + wagg[p][5];
            s0 = n0s; s1 = n1s;
        }
        wpv[wid][0] = s0; wpv[wid][1] = s1;
    }

    // b-coefficients + full 5-coef affine params (a-parts reused from registers)
    float vA[5], vB[5], vC[5];
    vA[0] = a1A; vB[0] = a1B; vC[0] = a1C;
    vA[1] = a2A; vB[1] = a2B; vC[1] = a2C;
    #pragma unroll
    for (int j = 0; j < 3; ++j) {
        vA[2 + j] = Lg[I * 5 + 2 + j];
        vB[2 + j] = Lg[(I + 1) * 5 + 2 + j];
        vC[2 + j] = Lg[I2 * 5 + 2 + j];
    }
    float Cs[5], Ds[5], Csb[5], Dsb[5];
    #pragma unroll
    for (int j = 0; j < 5; ++j) {
        Cs[j]  = fmaf(pos0 - If,       vB[j] - vA[j], vA[j]);
        Ds[j]  = KPOS * (vB[j] - vA[j]);
        Csb[j] = fmaf(pos0 - If - 1.f, vC[j] - vB[j], vB[j]);
        Dsb[j] = KPOS * (vC[j] - vB[j]);
    }
    __syncthreads();   // wpv ready

    float bs0 = wpv[wid][0], bs1 = wpv[wid][1];
    float s0v = e00 * bs0 + e01 * bs1 + ev0;   // y[n0-1]
    float s1v = e10 * bs0 + e11 * bs1 + ev1;   // y[n0-2]

    // ---- recurrence + fused FIR; x re-read (L2-hot), 64B-contiguous writes ----
    float4* op = (float4*)out + ((size_t)b * N_ + n0) / 4;
    #pragma unroll
    for (int j = 0; j < CS / 4; ++j) {
        float4 xv = xp[j];
        float4 yv;
        #pragma unroll
        for (int u = 0; u < 4; ++u) {
            int k = j * 4 + u;
            float xn = (&xv.x)[u];
            bool sB = (k >= kc);
            float kf = (float)k;
            float a1 = fmaf(kf, sB ? Dsb[0] : Ds[0], sB ? Csb[0] : Cs[0]);
            float a2 = fmaf(kf, sB ? Dsb[1] : Ds[1], sB ? Csb[1] : Cs[1]);
            float b0 = fmaf(kf, sB ? Dsb[2] : Ds[2], sB ? Csb[2] : Cs[2]);
            float b1 = fmaf(kf, sB ? Dsb[3] : Ds[3], sB ? Csb[3] : Cs[3]);
            float b2 = fmaf(kf, sB ? Dsb[4] : Ds[4], sB ? Csb[4] : Cs[4]);
            float y = fmaf(-a2, s1v, fmaf(-a1, s0v, xn));
            (&yv.x)[u] = fmaf(b2, s1v, fmaf(b1, s0v, b0 * y));
            s1v = s0v; s0v = y;
        }
        op[j] = yv;
    }
}

extern "C" void kernel_launch(void* const* d_in, const int* in_sizes, int n_in,
                              void* d_out, int out_size, void* d_ws, size_t ws_size,
                              hipStream_t stream) {
    const float* x      = (const float*)d_in[0];   // (B, N) f32
    const float* logits = (const float*)d_in[1];   // (B, F, 5) f32
    float* out = (float*)d_out;                    // (B, N) f32
    (void)d_ws; (void)ws_size;

    fused_row<<<B_, TPB, 0, stream>>>(x, logits, out);
}

// Round 10
// 96.077 us; speedup vs baseline: 1.4133x; 1.4133x over previous
//
#include <hip/hip_runtime.h>
#include <hip/hip_bf16.h>

#define B_   128
#define N_   65536
#define F_   512
#define CS   64                   // samples per thread
#define TPB  512                  // threads per block -> 32768 samples per block
#define NBLK 256                  // 2 blocks per row, one per CU (139KB LDS)
#define HALF 32768                // samples per block
#define NWAVE (TPB / 64)          // 8 waves
#define KPOS ((float)(511.0 / 65535.0))
#define INVK ((float)(65535.0 / 511.0))
#define STRIDE 68                 // padded LDS row stride (floats)
#define MAGIC 0x5A17F00Du         // ws poison 0xAAAAAAAA != MAGIC

// fallback (round-5) ws layout
#define CPR  (N_ / CS)
#define FB_TPB 128
#define FB_BPR (CPR / FB_TPB)
#define FB_NBLK (B_ * FB_BPR)
#define NT   (B_ * CPR)
#define OFF_PREF 0
#define OFF_AGG  (6 * NT)
// fused2 sync slots live after the fallback region: 128 rows x 32 floats (128B)
#define OFF_SYNC (OFF_AGG + FB_NBLK * 6)

__device__ __forceinline__ float tanh_map1(float l) { return 2.0f * tanhf(l); }

// Chunk geometry: I (i0 at chunk start), kc (first sample whose i0 is I+1; CS if
// no crossing), exactly matching reference floorf((n0+k)*K). (validated R5/R8/R9)
__device__ __forceinline__ void chunk_geom(int n0, float& pos0, int& I, int& kc) {
    pos0 = (float)n0 * KPOS;
    I = min((int)pos0, F_ - 2);
    int k = (int)ceilf(((float)(I + 1) - pos0) * INVK);
    k = max(0, min(k, CS));
    if (k > 0 && (int)((float)(n0 + k - 1) * KPOS) > I) --k;
    else if (k < CS && (int)((float)(n0 + k) * KPOS) <= I) ++k;
    if ((int)pos0 > F_ - 2) k = CS;
    if (I == F_ - 2) {
        if ((float)n0 * KPOS >= (float)(F_ - 1)) k = CS;
    }
    kc = k;
}

// ---------------- single fused kernel, one sync hop per row ----------------
__global__ __launch_bounds__(TPB) void fused2(const float* __restrict__ x,
                                              const float* __restrict__ logits,
                                              float* __restrict__ sync,
                                              float* __restrict__ out) {
    __shared__ __align__(16) float buf[TPB][STRIDE];   // 139,264 B
    __shared__ float wagg[NWAVE][6];
    __shared__ float sbs[2];
    int tid  = threadIdx.x;
    int gid  = blockIdx.x;
    int b    = gid >> 1;          // row
    int half = gid & 1;
    int lane = tid & 63;
    int wid  = tid >> 6;
    int n0   = half * HALF + tid * CS;   // sample offset within row

    // ---- stage x -> LDS (coalesced float4), the only global read of x ----
    const float4* xg = (const float4*)x + ((size_t)b * N_ + (size_t)half * HALF) / 4;
    #pragma unroll
    for (int it = 0; it < (TPB * CS / 4) / TPB; ++it) {   // 16 iters
        int i4 = it * TPB + tid;
        float4 v = xg[i4];
        *(float4*)&buf[i4 >> 4][(i4 & 15) * 4] = v;
    }
    __syncthreads();

    float pos0; int I, kc;
    chunk_geom(n0, pos0, I, kc);
    int I2 = min(I + 2, F_ - 1);
    const float* Lg = logits + (size_t)b * F_ * 5;

    float a1A = tanh_map1(Lg[I * 5 + 0]);
    float a1B = tanh_map1(Lg[(I + 1) * 5 + 0]);
    float a1C = tanh_map1(Lg[I2 * 5 + 0]);
    float t1A = tanhf(Lg[I * 5 + 1]);
    float t1B = tanhf(Lg[(I + 1) * 5 + 1]);
    float t1C = tanhf(Lg[I2 * 5 + 1]);
    float a2A = 0.5f * ((2.0f - fabsf(a1A)) * t1A + fabsf(a1A));
    float a2B = 0.5f * ((2.0f - fabsf(a1B)) * t1B + fabsf(a1B));
    float a2C = 0.5f * ((2.0f - fabsf(a1C)) * t1C + fabsf(a1C));

    float If = (float)I;
    float C1  = fmaf(pos0 - If,        a1B - a1A, a1A), D1  = KPOS * (a1B - a1A);
    float C1b = fmaf(pos0 - If - 1.f,  a1C - a1B, a1B), D1b = KPOS * (a1C - a1B);
    float C2  = fmaf(pos0 - If,        a2B - a2A, a2A), D2  = KPOS * (a2B - a2A);
    float C2b = fmaf(pos0 - If - 1.f,  a2C - a2B, a2B), D2b = KPOS * (a2C - a2B);

    // ---- compose this thread's 64-sample affine transform ----
    float A00 = 1.f, A01 = 0.f, A10 = 0.f, A11 = 1.f, v0 = 0.f, v1 = 0.f;
    #pragma unroll
    for (int j = 0; j < CS / 4; ++j) {
        float4 xv = *(const float4*)&buf[tid][j * 4];
        #pragma unroll
        for (int u = 0; u < 4; ++u) {
            int k = j * 4 + u;
            float xn = (&xv.x)[u];
            bool sB = (k >= kc);
            float kf = (float)k;
            float a1 = fmaf(kf, sB ? D1b : D1, sB ? C1b : C1);
            float a2 = fmaf(kf, sB ? D2b : D2, sB ? C2b : C2);
            float nA00 = fmaf(-a2, A10, -a1 * A00);
            float nA01 = fmaf(-a2, A11, -a1 * A01);
            float nv0  = fmaf(-a2, v1, fmaf(-a1, v0, xn));
            A10 = A00; A11 = A01; v1 = v0;
            A00 = nA00; A01 = nA01; v0 = nv0;
        }
    }

    // ---- wave-level inclusive scan (6 shuffle rounds, no barriers) ----
    #pragma unroll
    for (int d = 1; d < 64; d <<= 1) {
        float f00 = __shfl_up(A00, d);
        float f01 = __shfl_up(A01, d);
        float f10 = __shfl_up(A10, d);
        float f11 = __shfl_up(A11, d);
        float fv0 = __shfl_up(v0, d);
        float fv1 = __shfl_up(v1, d);
        if (lane >= d) {
            float n00 = A00 * f00 + A01 * f10;
            float n01 = A00 * f01 + A01 * f11;
            float n10 = A10 * f00 + A11 * f10;
            float n11 = A10 * f01 + A11 * f11;
            float nv0 = A00 * fv0 + A01 * fv1 + v0;
            float nv1 = A10 * fv0 + A11 * fv1 + v1;
            A00 = n00; A01 = n01; A10 = n10; A11 = n11; v0 = nv0; v1 = nv1;
        }
    }

    // lane-exclusive prefix
    float e00 = __shfl_up(A00, 1), e01 = __shfl_up(A01, 1);
    float e10 = __shfl_up(A10, 1), e11 = __shfl_up(A11, 1);
    float ev0 = __shfl_up(v0, 1),  ev1 = __shfl_up(v1, 1);
    if (lane == 0) { e00 = 1.f; e01 = 0.f; e10 = 0.f; e11 = 1.f; ev0 = 0.f; ev1 = 0.f; }

    if (lane == 63) {
        wagg[wid][0] = A00; wagg[wid][1] = A01; wagg[wid][2] = A10;
        wagg[wid][3] = A11; wagg[wid][4] = v0;  wagg[wid][5] = v1;
    }
    __syncthreads();

    // wave-prefix transform W = wagg[wid-1] o ... o wagg[0] (redundant per thread)
    float W00 = 1.f, W01 = 0.f, W10 = 0.f, W11 = 1.f, Wv0 = 0.f, Wv1 = 0.f;
    for (int p = 0; p < wid; ++p) {
        float g00 = wagg[p][0], g01 = wagg[p][1];
        float g10 = wagg[p][2], g11 = wagg[p][3];
        float gv0 = wagg[p][4], gv1 = wagg[p][5];
        // new = g_later o W_earlier?  NO: wagg[p] is EARLIER than wagg[p+1].
        // accumulate W = wagg[p] o W  ==> later o earlier, p ascending:
        float n00 = g00 * W00 + g01 * W10;
        float n01 = g00 * W01 + g01 * W11;
        float n10 = g10 * W00 + g11 * W10;
        float n11 = g10 * W01 + g11 * W11;
        float nv0 = g00 * Wv0 + g01 * Wv1 + gv0;
        float nv1 = g10 * Wv0 + g11 * Wv1 + gv1;
        W00 = n00; W01 = n01; W10 = n10; W11 = n11; Wv0 = nv0; Wv1 = nv1;
    }

    // block-exclusive transform E = e o W
    float E00 = e00 * W00 + e01 * W10;
    float E01 = e00 * W01 + e01 * W11;
    float E10 = e10 * W00 + e11 * W10;
    float E11 = e10 * W01 + e11 * W11;
    float Ev0 = e00 * Wv0 + e01 * Wv1 + ev0;
    float Ev1 = e10 * Wv0 + e11 * Wv1 + ev1;

    float* slot = sync + (size_t)b * 32;   // 128B-spaced per-row slot
    if (half == 0) {
        if (tid == TPB - 1) {
            // full-block composite G = incl o W ; start (0,0) => end state = G.v
            float Gv0 = A00 * Wv0 + A01 * Wv1 + v0;
            float Gv1 = A10 * Wv0 + A11 * Wv1 + v1;
            __hip_atomic_store(&slot[0], Gv0, __ATOMIC_RELAXED, __HIP_MEMORY_SCOPE_AGENT);
            __hip_atomic_store(&slot[1], Gv1, __ATOMIC_RELAXED, __HIP_MEMORY_SCOPE_AGENT);
            __hip_atomic_store((unsigned int*)&slot[2], MAGIC,
                               __ATOMIC_RELEASE, __HIP_MEMORY_SCOPE_AGENT);
        }
        if (tid == 0) { sbs[0] = 0.f; sbs[1] = 0.f; }
    } else {
        if (tid == 0) {
            while (__hip_atomic_load((unsigned int*)&slot[2],
                                     __ATOMIC_ACQUIRE, __HIP_MEMORY_SCOPE_AGENT) != MAGIC) {
                __builtin_amdgcn_s_sleep(8);
            }
            sbs[0] = __hip_atomic_load(&slot[0], __ATOMIC_RELAXED, __HIP_MEMORY_SCOPE_AGENT);
            sbs[1] = __hip_atomic_load(&slot[1], __ATOMIC_RELAXED, __HIP_MEMORY_SCOPE_AGENT);
        }
    }

    // full 5-coef affine params (a-parts reused from live registers)
    float vA[5], vB[5], vC[5];
    vA[0] = a1A; vB[0] = a1B; vC[0] = a1C;
    vA[1] = a2A; vB[1] = a2B; vC[1] = a2C;
    #pragma unroll
    for (int j = 0; j < 3; ++j) {
        vA[2 + j] = Lg[I * 5 + 2 + j];
        vB[2 + j] = Lg[(I + 1) * 5 + 2 + j];
        vC[2 + j] = Lg[I2 * 5 + 2 + j];
    }
    float Cs[5], Ds[5], Csb[5], Dsb[5];
    #pragma unroll
    for (int j = 0; j < 5; ++j) {
        Cs[j]  = fmaf(pos0 - If,       vB[j] - vA[j], vA[j]);
        Ds[j]  = KPOS * (vB[j] - vA[j]);
        Csb[j] = fmaf(pos0 - If - 1.f, vC[j] - vB[j], vB[j]);
        Dsb[j] = KPOS * (vC[j] - vB[j]);
    }
    __syncthreads();   // sbs ready

    float bs0 = sbs[0], bs1 = sbs[1];
    float s0v = E00 * bs0 + E01 * bs1 + Ev0;   // y[n0-1]
    float s1v = E10 * bs0 + E11 * bs1 + Ev1;   // y[n0-2]

    // ---- recurrence + fused FIR; y overwrites own LDS row ----
    #pragma unroll
    for (int j = 0; j < CS / 4; ++j) {
        float4 xv = *(const float4*)&buf[tid][j * 4];
        float4 yv;
        #pragma unroll
        for (int u = 0; u < 4; ++u) {
            int k = j * 4 + u;
            float xn = (&xv.x)[u];
            bool sB = (k >= kc);
            float kf = (float)k;
            float a1 = fmaf(kf, sB ? Dsb[0] : Ds[0], sB ? Csb[0] : Cs[0]);
            float a2 = fmaf(kf, sB ? Dsb[1] : Ds[1], sB ? Csb[1] : Cs[1]);
            float b0 = fmaf(kf, sB ? Dsb[2] : Ds[2], sB ? Csb[2] : Cs[2]);
            float b1 = fmaf(kf, sB ? Dsb[3] : Ds[3], sB ? Csb[3] : Cs[3]);
            float b2 = fmaf(kf, sB ? Dsb[4] : Ds[4], sB ? Csb[4] : Cs[4]);
            float y = fmaf(-a2, s1v, fmaf(-a1, s0v, xn));
            (&yv.x)[u] = fmaf(b2, s1v, fmaf(b1, s0v, b0 * y));
            s1v = s0v; s0v = y;
        }
        *(float4*)&buf[tid][j * 4] = yv;
    }
    __syncthreads();

    // ---- coalesced (lane-contiguous) writeback ----
    float4* og = (float4*)out + ((size_t)b * N_ + (size_t)half * HALF) / 4;
    #pragma unroll
    for (int it = 0; it < (TPB * CS / 4) / TPB; ++it) {
        int i4 = it * TPB + tid;
        og[i4] = *(float4*)&buf[i4 >> 4][(i4 & 15) * 4];
    }
}

// ---------------- fallback path (verbatim round 5, proven 101 µs) ----------------
__global__ __launch_bounds__(FB_TPB, 2) void phaseA(const float* __restrict__ x,
                                                    const float* __restrict__ logits,
                                                    float* __restrict__ pref,
                                                    float* __restrict__ agg) {
    __shared__ __align__(16) float buf[FB_TPB][STRIDE];
    __shared__ float sc[6][FB_TPB];
    int tid = threadIdx.x;
    int gid = blockIdx.x;
    int gchunk0 = gid * FB_TPB;

    const float4* xg = (const float4*)x + (size_t)gchunk0 * (CS / 4);
    #pragma unroll
    for (int it = 0; it < 16; ++it) {
        int i4 = it * FB_TPB + tid;
        float4 v = xg[i4];
        *(float4*)&buf[i4 >> 4][(i4 & 15) * 4] = v;
    }
    __syncthreads();

    int t = gchunk0 + tid;
    int c = t & (CPR - 1);
    int n0 = c * CS;

    float pos0; int I, kc;
    chunk_geom(n0, pos0, I, kc);
    int I2 = min(I + 2, F_ - 1);
    const float* Lg = logits + (size_t)(t >> 10) * F_ * 5;
    float a1A = tanh_map1(Lg[I * 5 + 0]);
    float a1B = tanh_map1(Lg[(I + 1) * 5 + 0]);
    float a1C = tanh_map1(Lg[I2 * 5 + 0]);
    float t1A = tanhf(Lg[I * 5 + 1]);
    float t1B = tanhf(Lg[(I + 1) * 5 + 1]);
    float t1C = tanhf(Lg[I2 * 5 + 1]);
    float a2A = 0.5f * ((2.0f - fabsf(a1A)) * t1A + fabsf(a1A));
    float a2B = 0.5f * ((2.0f - fabsf(a1B)) * t1B + fabsf(a1B));
    float a2C = 0.5f * ((2.0f - fabsf(a1C)) * t1C + fabsf(a1C));

    float If = (float)I;
    float C1  = fmaf(pos0 - If,        a1B - a1A, a1A), D1  = KPOS * (a1B - a1A);
    float C1b = fmaf(pos0 - If - 1.f,  a1C - a1B, a1B), D1b = KPOS * (a1C - a1B);
    float C2  = fmaf(pos0 - If,        a2B - a2A, a2A), D2  = KPOS * (a2B - a2A);
    float C2b = fmaf(pos0 - If - 1.f,  a2C - a2B, a2B), D2b = KPOS * (a2C - a2B);

    float A00 = 1.f, A01 = 0.f, A10 = 0.f, A11 = 1.f, v0 = 0.f, v1 = 0.f;
    #pragma unroll
    for (int j = 0; j < CS / 4; ++j) {
        float4 xv = *(const float4*)&buf[tid][j * 4];
        #pragma unroll
        for (int u = 0; u < 4; ++u) {
            int k = j * 4 + u;
            float xn = (&xv.x)[u];
            bool sB = (k >= kc);
            float kf = (float)k;
            float a1 = fmaf(kf, sB ? D1b : D1, sB ? C1b : C1);
            float a2 = fmaf(kf, sB ? D2b : D2, sB ? C2b : C2);
            float nA00 = fmaf(-a2, A10, -a1 * A00);
            float nA01 = fmaf(-a2, A11, -a1 * A01);
            float nv0  = fmaf(-a2, v1, fmaf(-a1, v0, xn));
            A10 = A00; A11 = A01; v1 = v0;
            A00 = nA00; A01 = nA01; v0 = nv0;
        }
    }

    for (int d = 1; d < FB_TPB; d <<= 1) {
        sc[0][tid] = A00; sc[1][tid] = A01; sc[2][tid] = A10;
        sc[3][tid] = A11; sc[4][tid] = v0;  sc[5][tid] = v1;
        __syncthreads();
        if (tid >= d) {
            float f00 = sc[0][tid - d], f01 = sc[1][tid - d];
            float f10 = sc[2][tid - d], f11 = sc[3][tid - d];
            float fv0 = sc[4][tid - d], fv1 = sc[5][tid - d];
            float n00 = A00 * f00 + A01 * f10;
            float n01 = A00 * f01 + A01 * f11;
            float n10 = A10 * f00 + A11 * f10;
            float n11 = A10 * f01 + A11 * f11;
            float nv0 = A00 * fv0 + A01 * fv1 + v0;
            float nv1 = A10 * fv0 + A11 * fv1 + v1;
            A00 = n00; A01 = n01; A10 = n10; A11 = n11; v0 = nv0; v1 = nv1;
        }
        __syncthreads();
    }
    sc[0][tid] = A00; sc[1][tid] = A01; sc[2][tid] = A10;
    sc[3][tid] = A11; sc[4][tid] = v0;  sc[5][tid] = v1;
    __syncthreads();

    float e00, e01, e10, e11, ev0, ev1;
    if (tid == 0) { e00 = 1.f; e01 = 0.f; e10 = 0.f; e11 = 1.f; ev0 = 0.f; ev1 = 0.f; }
    else {
        e00 = sc[0][tid - 1]; e01 = sc[1][tid - 1];
        e10 = sc[2][tid - 1]; e11 = sc[3][tid - 1];
        ev0 = sc[4][tid - 1]; ev1 = sc[5][tid - 1];
    }
    pref[0 * NT + t] = e00; pref[1 * NT + t] = e01;
    pref[2 * NT + t] = e10; pref[3 * NT + t] = e11;
    pref[4 * NT + t] = ev0; pref[5 * NT + t] = ev1;
    if (tid == FB_TPB - 1) {
        float* T = agg + (size_t)gid * 6;
        T[0] = A00; T[1] = A01; T[2] = A10; T[3] = A11; T[4] = v0; T[5] = v1;
    }
}

__global__ __launch_bounds__(FB_TPB, 2) void phaseC(const float* __restrict__ x,
                                                    const float* __restrict__ logits,
                                                    const float* __restrict__ pref,
                                                    const float* __restrict__ agg,
                                                    float* __restrict__ out) {
    __shared__ __align__(16) float buf[FB_TPB][STRIDE];
    __shared__ float sbs[2];
    int tid = threadIdx.x;
    int gid = blockIdx.x;
    int gchunk0 = gid * FB_TPB;

    const float4* xg = (const float4*)x + (size_t)gchunk0 * (CS / 4);
    #pragma unroll
    for (int it = 0; it < 16; ++it) {
        int i4 = it * FB_TPB + tid;
        float4 v = xg[i4];
        *(float4*)&buf[i4 >> 4][(i4 & 15) * 4] = v;
    }

    if (tid == 0) {
        float s0 = 0.f, s1 = 0.f;
        int p0 = gid & ~(FB_BPR - 1);
        for (int p = p0; p < gid; ++p) {
            const float* T = agg + (size_t)p * 6;
            float n0s = T[0] * s0 + T[1] * s1 + T[4];
            float n1s = T[2] * s0 + T[3] * s1 + T[5];
            s0 = n0s; s1 = n1s;
        }
        sbs[0] = s0; sbs[1] = s1;
    }

    int t = gchunk0 + tid;
    int c = t & (CPR - 1);
    int n0 = c * CS;

    float pos0; int I, kc;
    chunk_geom(n0, pos0, I, kc);
    int I2 = min(I + 2, F_ - 1);
    const float* Lg = logits + (size_t)(t >> 10) * F_ * 5;
    float vA[5], vB[5], vC[5];
    {
        float a1A = tanh_map1(Lg[I * 5 + 0]);
        float a1B = tanh_map1(Lg[(I + 1) * 5 + 0]);
        float a1C = tanh_map1(Lg[I2 * 5 + 0]);
        float t1A = tanhf(Lg[I * 5 + 1]);
        float t1B = tanhf(Lg[(I + 1) * 5 + 1]);
        float t1C = tanhf(Lg[I2 * 5 + 1]);
        vA[0] = a1A; vB[0] = a1B; vC[0] = a1C;
        vA[1] = 0.5f * ((2.0f - fabsf(a1A)) * t1A + fabsf(a1A));
        vB[1] = 0.5f * ((2.0f - fabsf(a1B)) * t1B + fabsf(a1B));
        vC[1] = 0.5f * ((2.0f - fabsf(a1C)) * t1C + fabsf(a1C));
        #pragma unroll
        for (int j = 0; j < 3; ++j) {
            vA[2 + j] = Lg[I * 5 + 2 + j];
            vB[2 + j] = Lg[(I + 1) * 5 + 2 + j];
            vC[2 + j] = Lg[I2 * 5 + 2 + j];
        }
    }
    float If = (float)I;
    float Cs[5], Ds[5], Csb[5], Dsb[5];
    #pragma unroll
    for (int j = 0; j < 5; ++j) {
        Cs[j]  = fmaf(pos0 - If,       vB[j] - vA[j], vA[j]);
        Ds[j]  = KPOS * (vB[j] - vA[j]);
        Csb[j] = fmaf(pos0 - If - 1.f, vC[j] - vB[j], vB[j]);
        Dsb[j] = KPOS * (vC[j] - vB[j]);
    }

    float L00 = pref[0 * NT + t], L01 = pref[1 * NT + t];
    float L10 = pref[2 * NT + t], L11 = pref[3 * NT + t];
    float Lv0 = pref[4 * NT + t], Lv1 = pref[5 * NT + t];

    __syncthreads();

    float bs0 = sbs[0], bs1 = sbs[1];
    float s0v = L00 * bs0 + L01 * bs1 + Lv0;
    float s1v = L10 * bs0 + L11 * bs1 + Lv1;

    #pragma unroll
    for (int j = 0; j < CS / 4; ++j) {
        float4 xv = *(const float4*)&buf[tid][j * 4];
        float4 yv;
        #pragma unroll
        for (int u = 0; u < 4; ++u) {
            int k = j * 4 + u;
            float xn = (&xv.x)[u];
            bool sB = (k >= kc);
            float kf = (float)k;
            float a1 = fmaf(kf, sB ? Dsb[0] : Ds[0], sB ? Csb[0] : Cs[0]);
            float a2 = fmaf(kf, sB ? Dsb[1] : Ds[1], sB ? Csb[1] : Cs[1]);
            float b0 = fmaf(kf, sB ? Dsb[2] : Ds[2], sB ? Csb[2] : Cs[2]);
            float b1 = fmaf(kf, sB ? Dsb[3] : Ds[3], sB ? Csb[3] : Cs[3]);
            float b2 = fmaf(kf, sB ? Dsb[4] : Ds[4], sB ? Csb[4] : Cs[4]);
            float y = fmaf(-a2, s1v, fmaf(-a1, s0v, xn));
            (&yv.x)[u] = fmaf(b2, s1v, fmaf(b1, s0v, b0 * y));
            s1v = s0v; s0v = y;
        }
        *(float4*)&buf[tid][j * 4] = yv;
    }
    __syncthreads();

    float4* og = (float4*)out + (size_t)gchunk0 * (CS / 4);
    #pragma unroll
    for (int it = 0; it < 16; ++it) {
        int i4 = it * FB_TPB + tid;
        og[i4] = *(float4*)&buf[i4 >> 4][(i4 & 15) * 4];
    }
}

extern "C" void kernel_launch(void* const* d_in, const int* in_sizes, int n_in,
                              void* d_out, int out_size, void* d_ws, size_t ws_size,
                              hipStream_t stream) {
    const float* x      = (const float*)d_in[0];   // (B, N) f32
    const float* logits = (const float*)d_in[1];   // (B, F, 5) f32
    float* out = (float*)d_out;                    // (B, N) f32
    float* ws  = (float*)d_ws;

    float* sync = ws + OFF_SYNC;                   // 128 rows x 128B slots

    fused2<<<NBLK, TPB, 0, stream>>>(x, logits, sync, out);
    if (hipGetLastError() != hipSuccess) {
        // deterministic fallback: round-5 two-kernel path (proven)
        float* pref = ws + OFF_PREF;
        float* agg  = ws + OFF_AGG;
        phaseA<<<FB_NBLK, FB_TPB, 0, stream>>>(x, logits, pref, agg);
        phaseC<<<FB_NBLK, FB_TPB, 0, stream>>>(x, logits, pref, agg, out);
    }
}